// Round 3
// baseline (755.713 us; speedup 1.0000x reference)
//
#include <hip/hip_runtime.h>
#include <cmath>

#define BATCH 32
#define CIN   512
#define BR    256
#define LEN   4096
#define TL    62        // output positions per block
#define RS    264       // LDS row stride (bf16 elements), 256 + 8 pad
#define NBLK  67        // ceil(LEN / TL)

typedef __attribute__((ext_vector_type(8))) short bf16x8;
typedef __attribute__((ext_vector_type(4))) float f32x4;

#define MFMA_BF16(a,b,c) __builtin_amdgcn_mfma_f32_16x16x32_bf16((a),(b),(c),0,0,0)

__device__ __forceinline__ float bf2f(unsigned short h){
  union { unsigned int u; float f; } c; c.u = ((unsigned int)h) << 16; return c.f;
}
__device__ __forceinline__ unsigned short f2bf(float f){
  union { float f; unsigned int u; } c; c.f = f;
  unsigned int r = c.u + 0x7fffu + ((c.u >> 16) & 1u);   // RNE
  return (unsigned short)(r >> 16);
}
// mish(x) = x*tanh(softplus(x)) = x*u/(u+2), u = p*(p+2), p = e^x (clamped).
__device__ __forceinline__ float mish_f(float v){
  float p = __expf(fminf(v, 40.0f));
  float u = p * (p + 2.0f);
  return v * (u / (u + 2.0f));
}
__device__ __forceinline__ void unpack8(const uint4 v, float* f){
  f[0] = bf2f((unsigned short)(v.x & 0xffffu)); f[1] = bf2f((unsigned short)(v.x >> 16));
  f[2] = bf2f((unsigned short)(v.y & 0xffffu)); f[3] = bf2f((unsigned short)(v.y >> 16));
  f[4] = bf2f((unsigned short)(v.z & 0xffffu)); f[5] = bf2f((unsigned short)(v.z >> 16));
  f[6] = bf2f((unsigned short)(v.w & 0xffffu)); f[7] = bf2f((unsigned short)(v.w >> 16));
}
__device__ __forceinline__ bf16x8 pack8(const float4 a, const float4 b){
  bf16x8 r;
  r[0] = (short)f2bf(a.x); r[1] = (short)f2bf(a.y);
  r[2] = (short)f2bf(a.z); r[3] = (short)f2bf(a.w);
  r[4] = (short)f2bf(b.x); r[5] = (short)f2bf(b.y);
  r[6] = (short)f2bf(b.z); r[7] = (short)f2bf(b.w);
  return r;
}

__global__ __launch_bounds__(256, 2)
void fused_shuffle_kernel(const float* __restrict__ xg,
                          const int*   __restrict__ maskg,
                          const float* __restrict__ w1g,
                          const float* __restrict__ w2g,
                          const float* __restrict__ w3g,
                          const float* __restrict__ bn1w, const float* __restrict__ bn1b,
                          const float* __restrict__ bn1rm, const float* __restrict__ bn1rv,
                          const float* __restrict__ bn2w, const float* __restrict__ bn2b,
                          const float* __restrict__ bn2rm, const float* __restrict__ bn2rv,
                          const float* __restrict__ bn3w, const float* __restrict__ bn3b,
                          const float* __restrict__ bn3rm, const float* __restrict__ bn3rv,
                          float*       __restrict__ outg)
{
  __shared__ __align__(16) unsigned short ls_x2[64 * RS];   // x2 tile [pos][ch] bf16; reused as t2
  __shared__ __align__(16) unsigned short ls_t1[64 * RS];   // t1 tile [pos][ch] bf16
  __shared__ float ls_a1[BR], ls_b1[BR], ls_a2[BR], ls_b2[BR], ls_a3[BR], ls_b3[BR];
  __shared__ float ls_w2[3][BR];

  const int tid = threadIdx.x;
  const int bx  = blockIdx.x;          // l-tile 0..66
  const int b   = blockIdx.y;          // batch
  const int l0  = bx * TL;

  // ---------- embedded x1 -> odd output channels (f32 bit copy, float4, grid-stride) ----------
  {
    const size_t nchunks = (size_t)BATCH * BR * LEN / 4;          // 8,388,608 float4 chunks
    const size_t stride  = (size_t)NBLK * BATCH * 256;            // 548,864
    for (size_t idx = ((size_t)b * NBLK + bx) * 256 + tid; idx < nchunks; idx += stride) {
      const int l  = (int)((idx & 1023) * 4);
      const int c  = (int)((idx >> 10) & 255);
      const int bb = (int)(idx >> 18);
      const float4 v = *(const float4*)(xg + (size_t)(bb * CIN + c) * LEN + l);
      *(float4*)(outg + (size_t)(bb * CIN + 2 * c + 1) * LEN + l) = v;
    }
  }

  // ---------- zero-init LDS tiles: any hole reads 0 (== conv zero-padding) ----------
  {
    uint4* z1 = (uint4*)ls_x2;
    uint4* z2 = (uint4*)ls_t1;
    const uint4 z = make_uint4(0, 0, 0, 0);
    for (int i = tid; i < (64 * RS) / 8; i += 256) { z1[i] = z; z2[i] = z; }
  }

  // ---------- folded BN params + conv weights (all f32) ----------
  {
    const int c = tid;   // 256 threads == 256 channels
    {
      float a = bn1w[c] / sqrtf(bn1rv[c] + 1e-5f);
      ls_a1[c] = a; ls_b1[c] = bn1b[c] - bn1rm[c] * a;
    }
    {
      float a = bn2w[c] / sqrtf(bn2rv[c] + 1e-5f);
      ls_a2[c] = a; ls_b2[c] = bn2b[c] - bn2rm[c] * a;
    }
    {
      float a = bn3w[c] / sqrtf(bn3rv[c] + 1e-5f);
      ls_a3[c] = a; ls_b3[c] = bn3b[c] - bn3rm[c] * a;
    }
    ls_w2[0][c] = w2g[c * 3 + 0];
    ls_w2[1][c] = w2g[c * 3 + 1];
    ls_w2[2][c] = w2g[c * 3 + 2];
  }
  __syncthreads();   // zero-init + params visible before staging stores

  // ---------- stage x2 (f32) -> LDS bf16, transposed [pos][ch] ----------
  // 17 float4 chunks per channel cover positions [lbase4, lbase4+68) ⊇ [l0-1, l0+62].
  // True-position stores: clamped chunks produce duplicate writes of identical values;
  // positions whose true l is OOB stay zero.
  {
    const int lbase4 = (l0 - 1) & ~3;
    for (int q = tid; q < 256 * 17; q += 256) {
      const int c   = q / 17;
      const int j   = q - c * 17;
      const int lg  = lbase4 + j * 4;
      const int lgc = min(max(lg, 0), LEN - 4);
      const float4 v = *(const float4*)(xg + (size_t)(b * CIN + BR + c) * LEN + lgc);
      const float vv[4] = {v.x, v.y, v.z, v.w};
      #pragma unroll
      for (int jj = 0; jj < 4; ++jj) {
        const int p = (lgc + jj) - (l0 - 1);
        if (p >= 0 && p < 64) ls_x2[p * RS + c] = f2bf(vv[jj]);
      }
    }
  }
  __syncthreads();

  const int lane = tid & 63;
  const int wid  = tid >> 6;     // wave 0..3
  const int xl   = lane & 15;    // MFMA m/n index
  const int qd   = lane >> 4;    // MFMA quad

  // ---------- GEMM1: t1 = mask*bn1(mish(W1 @ x2)) -> ls_t1 [pos][ch] ----------
  {
    int mk1[4];
    #pragma unroll
    for (int j = 0; j < 4; ++j) {
      const int l = l0 - 1 + 16 * j + xl;
      mk1[j] = (l >= 0 && l < LEN) ? maskg[b * LEN + l] : 0;   // OOB -> 0 == conv zero-pad
    }
    bf16x8 af[4][8];            // W1 fragments (f32 -> bf16 inline, L2-hot)
    #pragma unroll
    for (int mi = 0; mi < 4; ++mi) {
      const int ob = (wid * 4 + mi) * 16;
      #pragma unroll
      for (int k = 0; k < 8; ++k) {
        const float* wp = w1g + (size_t)(ob + xl) * 256 + k * 32 + qd * 8;
        af[mi][k] = pack8(*(const float4*)wp, *(const float4*)(wp + 4));
      }
    }
    #pragma unroll
    for (int j = 0; j < 4; ++j) {
      const int p = 16 * j + xl;
      bf16x8 bf[8];
      #pragma unroll
      for (int k = 0; k < 8; ++k)
        bf[k] = *(const bf16x8*)&ls_x2[p * RS + k * 32 + qd * 8];
      #pragma unroll
      for (int mi = 0; mi < 4; ++mi) {
        const int ob = (wid * 4 + mi) * 16;
        f32x4 acc = {0.f, 0.f, 0.f, 0.f};
        #pragma unroll
        for (int k = 0; k < 8; ++k) acc = MFMA_BF16(af[mi][k], bf[k], acc);
        const f32x4 av = *(const f32x4*)&ls_a1[ob + 4 * qd];
        const f32x4 bv = *(const f32x4*)&ls_b1[ob + 4 * qd];
        unsigned short us[4];
        #pragma unroll
        for (int r = 0; r < 4; ++r) {
          float v = mish_f(acc[r]);
          v = av[r] * v + bv[r];
          if (!mk1[j]) v = 0.0f;
          us[r] = f2bf(v);
        }
        const unsigned int lo = (unsigned int)us[0] | ((unsigned int)us[1] << 16);
        const unsigned int hi = (unsigned int)us[2] | ((unsigned int)us[3] << 16);
        *(uint2*)&ls_t1[p * RS + ob + 4 * qd] = make_uint2(lo, hi);
      }
    }
  }
  __syncthreads();

  // ---------- depthwise conv3 + bn2 + mask: t2 -> ls_x2 (reuse) ----------
  {
    const int c0    = (tid & 31) * 8;
    const int qbase = tid >> 5;
    const f32x4 k0a = *(const f32x4*)&ls_w2[0][c0], k0b = *(const f32x4*)&ls_w2[0][c0 + 4];
    const f32x4 k1a = *(const f32x4*)&ls_w2[1][c0], k1b = *(const f32x4*)&ls_w2[1][c0 + 4];
    const f32x4 k2a = *(const f32x4*)&ls_w2[2][c0], k2b = *(const f32x4*)&ls_w2[2][c0 + 4];
    const f32x4 a2a = *(const f32x4*)&ls_a2[c0],    a2b = *(const f32x4*)&ls_a2[c0 + 4];
    const f32x4 b2a = *(const f32x4*)&ls_b2[c0],    b2b = *(const f32x4*)&ls_b2[c0 + 4];
    #pragma unroll
    for (int it = 0; it < 8; ++it) {
      const int qo = qbase + 8 * it;          // 0..63, each (qo,c0) exactly once
      if (qo >= TL) {                          // rows 62,63: zero (keeps GEMM2 clean)
        *(uint4*)&ls_x2[qo * RS + c0] = make_uint4(0, 0, 0, 0);
      } else {
        const int l  = l0 + qo;
        const int mk = (l < LEN) ? maskg[b * LEN + l] : 0;
        const uint4 ra = *(const uint4*)&ls_t1[(qo    ) * RS + c0];
        const uint4 rb = *(const uint4*)&ls_t1[(qo + 1) * RS + c0];
        const uint4 rc = *(const uint4*)&ls_t1[(qo + 2) * RS + c0];
        float ta[8], tb[8], tc[8];
        unpack8(ra, ta); unpack8(rb, tb); unpack8(rc, tc);
        unsigned short us[8];
        #pragma unroll
        for (int i = 0; i < 4; ++i) {
          float y  = a2a[i] * (k0a[i] * ta[i]     + k1a[i] * tb[i]     + k2a[i] * tc[i]    ) + b2a[i];
          float y2 = a2b[i] * (k0b[i] * ta[4 + i] + k1b[i] * tb[4 + i] + k2b[i] * tc[4 + i]) + b2b[i];
          if (!mk) { y = 0.0f; y2 = 0.0f; }
          us[i]     = f2bf(y);
          us[4 + i] = f2bf(y2);
        }
        uint4 wv;
        wv.x = (unsigned int)us[0] | ((unsigned int)us[1] << 16);
        wv.y = (unsigned int)us[2] | ((unsigned int)us[3] << 16);
        wv.z = (unsigned int)us[4] | ((unsigned int)us[5] << 16);
        wv.w = (unsigned int)us[6] | ((unsigned int)us[7] << 16);
        *(uint4*)&ls_x2[qo * RS + c0] = wv;
      }
    }
  }
  __syncthreads();

  // ---------- GEMM2: out_even = mask*bn3(mish(W3 @ t2)), interleaved f32 store ----------
  {
    int mk2[4];
    #pragma unroll
    for (int j = 0; j < 4; ++j) {
      const int l = l0 + 16 * j + xl;
      mk2[j] = (l < LEN) ? maskg[b * LEN + l] : 0;
    }
    bf16x8 af[4][8];
    #pragma unroll
    for (int mi = 0; mi < 4; ++mi) {
      const int ob = (wid * 4 + mi) * 16;
      #pragma unroll
      for (int k = 0; k < 8; ++k) {
        const float* wp = w3g + (size_t)(ob + xl) * 256 + k * 32 + qd * 8;
        af[mi][k] = pack8(*(const float4*)wp, *(const float4*)(wp + 4));
      }
    }
    #pragma unroll
    for (int j = 0; j < 4; ++j) {
      const int p = 16 * j + xl;
      const int l = l0 + p;
      const bool st = (p < TL) && (l < LEN);
      bf16x8 bf[8];
      #pragma unroll
      for (int k = 0; k < 8; ++k)
        bf[k] = *(const bf16x8*)&ls_x2[p * RS + k * 32 + qd * 8];
      #pragma unroll
      for (int mi = 0; mi < 4; ++mi) {
        const int ob = (wid * 4 + mi) * 16;
        f32x4 acc = {0.f, 0.f, 0.f, 0.f};
        #pragma unroll
        for (int k = 0; k < 8; ++k) acc = MFMA_BF16(af[mi][k], bf[k], acc);
        const f32x4 av = *(const f32x4*)&ls_a3[ob + 4 * qd];
        const f32x4 bv = *(const f32x4*)&ls_b3[ob + 4 * qd];
        #pragma unroll
        for (int r = 0; r < 4; ++r) {
          float v = mish_f(acc[r]);
          v = av[r] * v + bv[r];
          if (!mk2[j]) v = 0.0f;
          if (st) {
            const int o2 = ob + 4 * qd + r;
            outg[(size_t)(b * CIN + 2 * o2) * LEN + l] = v;
          }
        }
      }
    }
  }
}

extern "C" void kernel_launch(void* const* d_in, const int* in_sizes, int n_in,
                              void* d_out, int out_size, void* d_ws, size_t ws_size,
                              hipStream_t stream) {
  (void)in_sizes; (void)n_in; (void)out_size; (void)d_ws; (void)ws_size;
  const float* xg    = (const float*)d_in[0];
  const int*   maskg = (const int*)d_in[1];
  const float* w1    = (const float*)d_in[2];
  const float* w2    = (const float*)d_in[3];
  const float* w3    = (const float*)d_in[4];
  const float* b1w   = (const float*)d_in[5];
  const float* b1b   = (const float*)d_in[6];
  const float* b1rm  = (const float*)d_in[7];
  const float* b1rv  = (const float*)d_in[8];
  const float* b2w   = (const float*)d_in[9];
  const float* b2b   = (const float*)d_in[10];
  const float* b2rm  = (const float*)d_in[11];
  const float* b2rv  = (const float*)d_in[12];
  const float* b3w   = (const float*)d_in[13];
  const float* b3b   = (const float*)d_in[14];
  const float* b3rm  = (const float*)d_in[15];
  const float* b3rv  = (const float*)d_in[16];
  float* outp = (float*)d_out;

  dim3 grid(NBLK, BATCH, 1);
  hipLaunchKernelGGL(fused_shuffle_kernel, grid, dim3(256, 1, 1), 0, stream,
                     xg, maskg, w1, w2, w3,
                     b1w, b1b, b1rm, b1rv, b2w, b2b, b2rm, b2rv, b3w, b3b, b3rm, b3rv,
                     outp);
}